// Round 11
// baseline (363.378 us; speedup 1.0000x reference)
//
#include <hip/hip_runtime.h>
#include <hip/hip_bf16.h>
#include <cstdint>

// Problem constants
#define B_ 4
#define S_ 4096
#define D_ 1024
#define DFF_ 4096
#define KSEL_ 2048
#define M_ (B_ * KSEL_)      // 8192 selected rows total
#define NTOK_ (B_ * S_)      // 16384

typedef short bf16x8 __attribute__((ext_vector_type(8)));
typedef float f32x4 __attribute__((ext_vector_type(4)));

__device__ inline unsigned short f2bf(float f) {
    union { float f; unsigned int u; } c; c.f = f;
    unsigned int u = c.u;
    unsigned int r = u + 0x7fffu + ((u >> 16) & 1u);
    return (unsigned short)(r >> 16);
}

// ---------------------------------------------------------------------------
// Fused transpose + fp32->bf16 for W1 and W2 in ONE launch (saves a dispatch).
// id < 4096: W1 [D_][DFF_] -> W1bT [DFF_][D_]; else W2 [DFF_][D_] -> W2bT.
// ---------------------------------------------------------------------------
__global__ __launch_bounds__(256)
void transpose2_bf16(const float* __restrict__ W1, unsigned short* __restrict__ W1bT,
                     const float* __restrict__ W2, unsigned short* __restrict__ W2bT) {
    __shared__ float tile[32][33];
    int id = blockIdx.x;
    const float* src; unsigned short* dst; int R, C, bx, by;
    if (id < (DFF_ / 32) * (D_ / 32)) {
        src = W1; dst = W1bT; R = D_; C = DFF_;
        bx = id % (DFF_ / 32); by = id / (DFF_ / 32);
    } else {
        id -= (DFF_ / 32) * (D_ / 32);
        src = W2; dst = W2bT; R = DFF_; C = D_;
        bx = id % (D_ / 32); by = id / (D_ / 32);
    }
    int c0 = bx * 32, r0 = by * 32;
    for (int i = threadIdx.y; i < 32; i += 8)
        tile[i][threadIdx.x] = src[(size_t)(r0 + i) * C + c0 + threadIdx.x];
    __syncthreads();
    for (int i = threadIdx.y; i < 32; i += 8)
        dst[(size_t)(c0 + i) * R + r0 + threadIdx.x] = f2bf(tile[threadIdx.x][i]);
}

// ---------------------------------------------------------------------------
// Router: logits[row] = dot(x[row], Wr); write xb = bf16(x); write out = x
// ---------------------------------------------------------------------------
__global__ __launch_bounds__(256)
void router_kernel(const float* __restrict__ x, const float* __restrict__ Wr,
                   float* __restrict__ logits, unsigned short* __restrict__ xb,
                   float* __restrict__ out) {
    int wid = threadIdx.x >> 6, lane = threadIdx.x & 63;
    int row = blockIdx.x * 4 + wid;
    const float* xr = x + (size_t)row * D_;
    unsigned short* xbr = xb + (size_t)row * D_;
    float* outr = out + (size_t)row * D_;
    float acc = 0.f;
#pragma unroll
    for (int j = 0; j < 4; j++) {
        int off = j * 256 + lane * 4;
        float4 v = *(const float4*)(xr + off);
        float4 w = *(const float4*)(Wr + off);
        acc += v.x * w.x + v.y * w.y + v.z * w.z + v.w * w.w;
        *(float4*)(outr + off) = v;
        ushort4 o;
        o.x = f2bf(v.x); o.y = f2bf(v.y); o.z = f2bf(v.z); o.w = f2bf(v.w);
        *(ushort4*)(xbr + off) = o;
    }
#pragma unroll
    for (int s = 32; s; s >>= 1) acc += __shfl_xor(acc, s);
    if (lane == 0) logits[row] = acc;
}

// ---------------------------------------------------------------------------
// Rank (split-j): partial rank over a 512-logit j-chunk, atomicAdd into rank[].
// ---------------------------------------------------------------------------
__global__ __launch_bounds__(256)
void rank_partial_kernel(const float* __restrict__ logits, int* __restrict__ rank) {
    __shared__ float lj[512];
    int b  = blockIdx.x >> 7;
    int ic = (blockIdx.x >> 3) & 15;
    int jc = blockIdx.x & 7;
    const float* L = logits + b * S_;
    for (int t = threadIdx.x; t < 512; t += 256) lj[t] = L[jc * 512 + t];
    __syncthreads();
    int i = ic * 256 + threadIdx.x;
    float li = L[i];
    int jbase = jc * 512;
    int r = 0;
    const float4* __restrict__ lj4 = (const float4*)lj;
#pragma unroll 4
    for (int q = 0; q < 128; q++) {
        float4 v = lj4[q];
        int jb = jbase + q * 4;
        r += (v.x > li) | ((v.x == li) & (jb     < i));
        r += (v.y > li) | ((v.y == li) & (jb + 1 < i));
        r += (v.z > li) | ((v.z == li) & (jb + 2 < i));
        r += (v.w > li) | ((v.w == li) & (jb + 3 < i));
    }
    atomicAdd(&rank[b * S_ + i], r);
}

// ---------------------------------------------------------------------------
// Compact: sel = rank < KSEL_; flags, softmax weights, prefix-sum -> rowidx/rw.
// ---------------------------------------------------------------------------
__global__ __launch_bounds__(256)
void compact_kernel(const float* __restrict__ logits, const int* __restrict__ rank,
                    int* __restrict__ flags,
                    int* __restrict__ rowidx, float* __restrict__ rw) {
    __shared__ float lg[S_];
    __shared__ int f[S_];
    __shared__ int tsum[256];
    __shared__ float red[256];
    int b = blockIdx.x;
    const float* L = logits + b * S_;
    const int* R = rank + b * S_;
    int* F = flags + b * S_;
    for (int j = threadIdx.x; j < S_ / 4; j += 256) {
        ((float4*)lg)[j] = ((const float4*)L)[j];
        int4 rk = ((const int4*)R)[j];
        int4 fl;
        fl.x = rk.x < KSEL_; fl.y = rk.y < KSEL_;
        fl.z = rk.z < KSEL_; fl.w = rk.w < KSEL_;
        ((int4*)f)[j] = fl;
        ((int4*)F)[j] = fl;
    }
    __syncthreads();
    float mx = -INFINITY;
    for (int j = threadIdx.x; j < S_; j += 256) mx = fmaxf(mx, lg[j]);
    red[threadIdx.x] = mx; __syncthreads();
    for (int s = 128; s; s >>= 1) {
        if (threadIdx.x < s) red[threadIdx.x] = fmaxf(red[threadIdx.x], red[threadIdx.x + s]);
        __syncthreads();
    }
    float m = red[0];
    __syncthreads();

    float esum = 0.f;
    int s0 = 0;
#pragma unroll
    for (int j = 0; j < 16; j++) {
        int i = threadIdx.x * 16 + j;
        s0 += f[i];
        if (f[i]) esum += expf(lg[i] - m);
    }
    red[threadIdx.x] = esum; __syncthreads();
    for (int s = 128; s; s >>= 1) {
        if (threadIdx.x < s) red[threadIdx.x] += red[threadIdx.x + s];
        __syncthreads();
    }
    float inv = 1.f / red[0];

    tsum[threadIdx.x] = s0; __syncthreads();
    for (int s = 1; s < 256; s <<= 1) {
        int u = (threadIdx.x >= s) ? tsum[threadIdx.x - s] : 0;
        __syncthreads();
        tsum[threadIdx.x] += u;
        __syncthreads();
    }
    int pos = tsum[threadIdx.x] - s0;
    for (int j = 0; j < 16; j++) {
        int i = threadIdx.x * 16 + j;
        if (f[i]) {
            rowidx[b * KSEL_ + pos] = b * S_ + i;
            rw[b * KSEL_ + pos] = expf(lg[i] - m) * inv;
            pos++;
        }
    }
}

// ---------------------------------------------------------------------------
// Fused aux loss: BCE-with-logits mean, flat-index union targets; one block.
// ---------------------------------------------------------------------------
__global__ __launch_bounds__(1024)
void loss_fused(const float* __restrict__ logits, const int* __restrict__ flags,
                float* __restrict__ out) {
    __shared__ float red[1024];
    float acc = 0.f;
    for (int i = threadIdx.x; i < NTOK_; i += 1024) {
        float l = logits[i];
        float t = 0.f;
        if (i < S_)
            t = (flags[i] | flags[S_ + i] | flags[2 * S_ + i] | flags[3 * S_ + i]) ? 1.f : 0.f;
        acc += fmaxf(l, 0.f) - l * t + log1pf(expf(-fabsf(l)));
    }
    red[threadIdx.x] = acc; __syncthreads();
    for (int s = 512; s; s >>= 1) {
        if (threadIdx.x < s) red[threadIdx.x] += red[threadIdx.x + s];
        __syncthreads();
    }
    if (threadIdx.x == 0) out[0] = red[0] / (float)NTOK_;
}

// ---------------------------------------------------------------------------
// GEMM1: 256x256 tile, per-wave 128x64 (LDS-traffic ratio 0.375 KB/MFMA vs
// 0.5 at 64x64 -> structural ceiling 55% vs 47%).  BK_sub=32, 4-slot LDS ring
// (4 x 32 KiB = 128 KiB), persistent SUBS=2 (grid 16x16 = 256 = 1 block/CU).
// Per sub-step t: 2 phases of 16 MFMA; phase0 reads af[0..3]+bfr[0..3] (8
// ds_read_b128), phase1 reads af[4..7] (4); staging of step t+3 split 2+2
// gloads across phases into slot (t+3)&3 (readers finished at step t-1's
// barrier; issue is after it -> race-free).  Counted vmcnt(8) at step end:
// slot t+1's 4 loads are older than the 8 in flight (t+2, t+3) -> complete.
// vmcnt precedes s_barrier so every wave's own loads are done before any wave
// crosses -> cross-wave LDS visibility correct.
// LDS rows are 64 B (4 chunks); XOR swizzle: phys_chunk = logical ^ ((row>>1)&3)
// (write side via pre-swizzled global source, read side same XOR; frag row
// bases are 0 mod 16 so read xor = (lr>>1)&3).  Per-instruction lanes spread
// uniformly 8 per bank-quad = LDS peak throughput.
// Epilogue per sub-tile: silu + bf16 store (stores are older than counted
// loads at the next vmcnt -> accounting stays exact; one-time drain accepted).
// ---------------------------------------------------------------------------
template <int N, int K, int SUBS>
__global__ __launch_bounds__(512, 2)
void gemm1_256_kernel(const unsigned short* __restrict__ A,
                      const unsigned short* __restrict__ BT,
                      const int* __restrict__ rowidx,
                      unsigned short* __restrict__ Hout) {
    static_assert(SUBS == 2, "address selection hardcoded for SUBS=2");
    constexpr int BKS = 32;
    constexpr int NSUB = K / BKS;           // 32
    constexpr int NSTEPS = SUBS * NSUB;     // 64
    constexpr int NT = N / 256;             // 16
    constexpr int MG = M_ / (256 * SUBS);   // 16
    constexpr int NWG = NT * MG;            // 256
    constexpr int CPX = NWG / 8;            // 32
    __shared__ __attribute__((aligned(16))) unsigned short As[4][256 * BKS];
    __shared__ __attribute__((aligned(16))) unsigned short Bs[4][256 * BKS];

    const int tid = threadIdx.x;
    const int w = tid >> 6, lane = tid & 63;
    const int wm = w >> 2, wn = w & 3;      // 2M x 4N waves

    // bijective XCD swizzle; n fastest within an XCD -> A read once chip-wide
    int wgid = blockIdx.y * NT + blockIdx.x;
    int swz = (wgid & 7) * CPX + (wgid >> 3);
    const int tile_n = (swz % NT) * 256;
    const int mgrp   = swz / NT;

    // staging: instr i in {0,1} covers LDS chunks i*512 + tid (16 B each);
    // row = i*128 + (tid>>2), phys chunk = tid&3 holds logical chunk
    // (tid&3) ^ ((row>>1)&3) = (tid&3) ^ ((tid>>3)&3)  (i*128>>1 = 0 mod 4).
    const int srow = tid >> 2;
    const int lchunk = (tid & 3) ^ ((tid >> 3) & 3);
    const uint64_t abase = (uint64_t)(uintptr_t)A;
    const uint64_t bbase = (uint64_t)(uintptr_t)BT;
    uint64_t aaddr[SUBS][2], baddr[2];
#pragma unroll
    for (int s = 0; s < SUBS; ++s)
#pragma unroll
        for (int i = 0; i < 2; ++i) {
            int r = i * 128 + srow;
            int ar = rowidx[(mgrp * SUBS + s) * 256 + r];
            aaddr[s][i] = abase + ((uint64_t)ar * K + (uint64_t)lchunk * 8) * 2ull;
        }
#pragma unroll
    for (int i = 0; i < 2; ++i) {
        int r = i * 128 + srow;
        baddr[i] = bbase + ((uint64_t)(tile_n + r) * K + (uint64_t)lchunk * 8) * 2ull;
    }

    auto gload = [&](unsigned short* lds, uint64_t gaddr) {
        __builtin_amdgcn_global_load_lds(
            (const __attribute__((address_space(1))) unsigned int*)(uintptr_t)gaddr,
            (__attribute__((address_space(3))) unsigned int*)lds, 16, 0, 0);
    };
    auto stageA = [&](int g, int slot) {
        const uint64_t koff = (uint64_t)(g & (NSUB - 1)) * (BKS * 2);
        const uint64_t a0 = (g >= NSUB) ? aaddr[1][0] : aaddr[0][0];
        const uint64_t a1 = (g >= NSUB) ? aaddr[1][1] : aaddr[0][1];
        gload(&As[slot][(0 * 512 + w * 64) * 8], a0 + koff);
        gload(&As[slot][(1 * 512 + w * 64) * 8], a1 + koff);
    };
    auto stageB = [&](int g, int slot) {
        const uint64_t koff = (uint64_t)(g & (NSUB - 1)) * (BKS * 2);
        gload(&Bs[slot][(0 * 512 + w * 64) * 8], baddr[0] + koff);
        gload(&Bs[slot][(1 * 512 + w * 64) * 8], baddr[1] + koff);
    };

    f32x4 acc[8][4];
#pragma unroll
    for (int i = 0; i < 8; i++)
#pragma unroll
        for (int j = 0; j < 4; j++) acc[i][j] = (f32x4){0.f, 0.f, 0.f, 0.f};

    const int lr = lane & 15, quad = lane >> 4;
    const int xo = (quad ^ ((lr >> 1) & 3)) * 16;   // frag read swizzle (bytes)

    auto flush = [&](int s) {
        const int tm = (mgrp * SUBS + s) * 256 + wm * 128;
#pragma unroll
        for (int m4 = 0; m4 < 8; ++m4)
#pragma unroll
            for (int r = 0; r < 4; ++r) {
                int m = tm + m4 * 16 + quad * 4 + r;
#pragma unroll
                for (int n4 = 0; n4 < 4; ++n4) {
                    int col = tile_n + wn * 64 + n4 * 16 + lr;
                    float v = acc[m4][n4][r];
                    v = v / (1.f + __expf(-v));   // silu
                    Hout[(uint64_t)m * N + col] = f2bf(v);
                }
            }
    };

    // prologue: steps 0,1,2 -> slots 0,1,2 (12 loads); slot 0 ready at vmcnt(8)
    stageA(0, 0); stageB(0, 0);
    stageA(1, 1); stageB(1, 1);
    stageA(2, 2); stageB(2, 2);
    asm volatile("s_waitcnt vmcnt(8)" ::: "memory");
    asm volatile("s_barrier" ::: "memory");

#pragma unroll 1
    for (int t = 0; t < NSTEPS; ++t) {
        const int c = t & 3, pslot = (t + 3) & 3;
        const bool dost = (t + 3 < NSTEPS);
        const char* Ab = (const char*)&As[c][0];
        const char* Bb = (const char*)&Bs[c][0];

        bf16x8 bfr[4];
        // ================= phase 0 : m-half 0 =================
        {
            bf16x8 af[4];
#pragma unroll
            for (int m4 = 0; m4 < 4; ++m4)
                af[m4] = *(const bf16x8*)(Ab + (wm * 128 + m4 * 16 + lr) * 64 + xo);
#pragma unroll
            for (int n4 = 0; n4 < 4; ++n4)
                bfr[n4] = *(const bf16x8*)(Bb + (wn * 64 + n4 * 16 + lr) * 64 + xo);
            if (dost) stageA(t + 3, pslot);
            asm volatile("s_barrier" ::: "memory");
            asm volatile("s_waitcnt lgkmcnt(0)" ::: "memory");
            __builtin_amdgcn_sched_barrier(0);
            __builtin_amdgcn_s_setprio(1);
#pragma unroll
            for (int m4 = 0; m4 < 4; ++m4)
#pragma unroll
                for (int n4 = 0; n4 < 4; ++n4)
                    acc[m4][n4] = __builtin_amdgcn_mfma_f32_16x16x32_bf16(
                        af[m4], bfr[n4], acc[m4][n4], 0, 0, 0);
            __builtin_amdgcn_s_setprio(0);
            asm volatile("s_barrier" ::: "memory");
        }

        // ================= phase 1 : m-half 1 =================
        {
            bf16x8 af[4];
#pragma unroll
            for (int m4 = 0; m4 < 4; ++m4)
                af[m4] = *(const bf16x8*)(Ab + (wm * 128 + 64 + m4 * 16 + lr) * 64 + xo);
            if (dost) stageB(t + 3, pslot);
            asm volatile("s_barrier" ::: "memory");
            asm volatile("s_waitcnt lgkmcnt(0)" ::: "memory");
            __builtin_amdgcn_sched_barrier(0);
            __builtin_amdgcn_s_setprio(1);
#pragma unroll
            for (int m4 = 0; m4 < 4; ++m4)
#pragma unroll
                for (int n4 = 0; n4 < 4; ++n4)
                    acc[4 + m4][n4] = __builtin_amdgcn_mfma_f32_16x16x32_bf16(
                        af[m4], bfr[n4], acc[4 + m4][n4], 0, 0, 0);
            __builtin_amdgcn_s_setprio(0);
            // counted waits: slot t+1 must be ready; t+2 (4) and t+3 (4) in flight
            if (t + 3 < NSTEPS) {
                asm volatile("s_waitcnt vmcnt(8)" ::: "memory");
            } else if (t + 2 < NSTEPS) {
                asm volatile("s_waitcnt vmcnt(4)" ::: "memory");
            } else if (t + 1 < NSTEPS) {
                asm volatile("s_waitcnt vmcnt(0)" ::: "memory");
            }
            asm volatile("s_barrier" ::: "memory");
        }

        // sub-tile boundary: flush + zero (stores drain at next counted vmcnt;
        // they are older than the counted loads -> accounting stays exact)
        if ((t & (NSUB - 1)) == (NSUB - 1) && (t + 1) < NSTEPS) {
            flush(t / NSUB);
#pragma unroll
            for (int i = 0; i < 8; i++)
#pragma unroll
                for (int j = 0; j < 4; j++) acc[i][j] = (f32x4){0.f, 0.f, 0.f, 0.f};
        }
    }
    flush(SUBS - 1);
}

// ---------------------------------------------------------------------------
// GEMM2 (unchanged from measured round-7 best): fine-phased 128x256 pipeline,
// 3-slot ring, counted vmcnt(6), persistent SUBS (=1 for GEMM2).
// MODE 2: scatter x + (H@W2)*rw.
// ---------------------------------------------------------------------------
template <int MODE, int N, int K, int SUBS>
__global__ __launch_bounds__(512, 2)
void gemm_pipe_kernel(const unsigned short* __restrict__ A,
                      const unsigned short* __restrict__ BT,
                      const int* __restrict__ rowidx,
                      const float* __restrict__ rw,
                      const float* __restrict__ x,
                      unsigned short* __restrict__ Hout,
                      float* __restrict__ Out) {
    constexpr int BM = 128, BN = 256, BK = 64;
    constexpr int KI = K / BK;
    constexpr int NT = N / BN;
    constexpr int MG = M_ / (BM * SUBS);
    constexpr int NWG = NT * MG;
    constexpr int CPX = NWG / 8;
    __shared__ __attribute__((aligned(16))) unsigned short As[3][BM * BK];
    __shared__ __attribute__((aligned(16))) unsigned short Bs[3][BN * BK];

    const int tid = threadIdx.x;
    const int w = tid >> 6, lane = tid & 63;
    const int wm = w >> 2, wn = w & 3;

    int wgid = blockIdx.y * NT + blockIdx.x;
    int swz = (wgid & 7) * CPX + (wgid >> 3);
    const int tile_n = (swz % NT) * BN;
    const int mgrp   = (swz / NT);

    const int srow = lane >> 3;
    const int sw = (lane & 7) ^ srow;
    const uint64_t abase = (uint64_t)(uintptr_t)A;
    const uint64_t bbase = (uint64_t)(uintptr_t)BT;
    uint64_t aaddr[SUBS][2], baddr[4];
#pragma unroll
    for (int s = 0; s < SUBS; ++s)
#pragma unroll
        for (int t = 0; t < 2; ++t) {
            int r = t * 64 + w * 8 + srow;
            int am = (mgrp * SUBS + s) * BM + r;
            int ar = (MODE == 1) ? rowidx[am] : am;
            aaddr[s][t] = abase + ((uint64_t)ar * K + (uint64_t)sw * 8) * 2ull;
        }
#pragma unroll
    for (int t = 0; t < 4; ++t) {
        int r = t * 64 + w * 8 + srow;
        baddr[t] = bbase + ((uint64_t)(tile_n + r) * K + (uint64_t)sw * 8) * 2ull;
    }

    auto gload = [&](unsigned short* lds, uint64_t gaddr) {
        __builtin_amdgcn_global_load_lds(
            (const __attribute__((address_space(1))) unsigned int*)(uintptr_t)gaddr,
            (__attribute__((address_space(3))) unsigned int*)lds, 16, 0, 0);
    };

    f32x4 acc[4][4];
#pragma unroll
    for (int i = 0; i < 4; i++)
#pragma unroll
        for (int j = 0; j < 4; j++) acc[i][j] = (f32x4){0.f, 0.f, 0.f, 0.f};

#pragma unroll
    for (int p = 0; p < 2; ++p) {
        const uint64_t koff = (uint64_t)p * (BK * 2);
        gload(&As[p][(0 * 64 + w * 8) * BK], aaddr[0][0] + koff);
        gload(&As[p][(1 * 64 + w * 8) * BK], aaddr[0][1] + koff);
#pragma unroll
        for (int t = 0; t < 4; ++t)
            gload(&Bs[p][(t * 64 + w * 8) * BK], baddr[t] + koff);
    }
    asm volatile("s_waitcnt vmcnt(6)" ::: "memory");
    asm volatile("s_barrier" ::: "memory");

    const int lr = lane & 15, quad = lane >> 4;
    int c = 0;
#pragma unroll
    for (int s = 0; s < SUBS; ++s) {
#pragma unroll 1
        for (int kt = 0; kt < KI; ++kt) {
            int pre = c + 2; if (pre >= 3) pre -= 3;
            const char* Abase_l = (const char*)&As[c][0];
            const char* Bbase_l = (const char*)&Bs[c][0];
            const bool cross = (kt + 2 >= KI);
            const bool do_stage = (s < SUBS - 1) || (kt + 2 < KI);
            const uint64_t sa0 = cross ? aaddr[(s + 1 < SUBS) ? s + 1 : s][0]
                                       : aaddr[s][0];
            const uint64_t sa1 = cross ? aaddr[(s + 1 < SUBS) ? s + 1 : s][1]
                                       : aaddr[s][1];
            const uint64_t koff = (uint64_t)((kt + 2) & (KI - 1)) * (BK * 2);

            // ================= phase 0 : ks = 0 =================
            {
                bf16x8 af[4], bfr[4];
                const int xo = (quad ^ (lr & 7)) * 16;
#pragma unroll
                for (int m4 = 0; m4 < 4; ++m4) {
                    int row = wm * 64 + m4 * 16 + lr;
                    af[m4] = *(const bf16x8*)(Abase_l + row * (BK * 2) + xo);
                }
#pragma unroll
                for (int n4 = 0; n4 < 4; ++n4) {
                    int col = wn * 64 + n4 * 16 + lr;
                    bfr[n4] = *(const bf16x8*)(Bbase_l + col * (BK * 2) + xo);
                }
                if (do_stage) {
                    gload(&As[pre][(0 * 64 + w * 8) * BK], sa0 + koff);
                    gload(&As[pre][(1 * 64 + w * 8) * BK], sa1 + koff);
                    gload(&Bs[pre][(w * 8) * BK], baddr[0] + koff);
                }
                asm volatile("s_barrier" ::: "memory");
                asm volatile("s_waitcnt lgkmcnt(0)" ::: "memory");
                __builtin_amdgcn_sched_barrier(0);
                __builtin_amdgcn_s_setprio(1);
#pragma unroll
                for (int m4 = 0; m4 < 4; ++m4)
#pragma unroll
                    for (int n4 = 0; n4 < 4; ++n4)
                        acc[m4][n4] = __builtin_amdgcn_mfma_f32_16x16x32_bf16(
                            af[m4], bfr[n4], acc[m4][n4], 0, 0, 0);
                __builtin_amdgcn_s_setprio(0);
                asm volatile("s_barrier" ::: "memory");
            }

            // ================= phase 1 : ks = 1 =================
            {
                bf16x8 af[4], bfr[4];
                const int xo = ((4 + quad) ^ (lr & 7)) * 16;
#pragma unroll
                for (int m4 = 0; m4 < 4; ++m4) {
                    int row = wm * 64 + m4 * 16 + lr;
                    af[m4] = *(const bf16x8*)(Abase_l + row * (BK * 2) + xo);
                }
#pragma unroll
                for (int n4 = 0; n4 < 4; ++n4) {
                    int col = wn * 64 + n4 * 16 + lr;
                    bfr[n4] = *(const bf16x8*)(Bbase_l + col * (BK * 2) + xo);
                }
                if (do_stage) {
#pragma unroll
                    for (int t = 1; t < 4; ++t)
                        gload(&Bs[pre][(t * 64 + w * 8) * BK], baddr[t] + koff);
                }
                asm volatile("s_barrier" ::: "memory");
                asm volatile("s_waitcnt lgkmcnt(0)" ::: "memory");
                __builtin_amdgcn_sched_barrier(0);
                __builtin_amdgcn_s_setprio(1);
#pragma unroll
                for (int m4 = 0; m4 < 4; ++m4)
#pragma unroll
                    for (int n4 = 0; n4 < 4; ++n4)
                        acc[m4][n4] = __builtin_amdgcn_mfma_f32_16x16x32_bf16(
                            af[m4], bfr[n4], acc[m4][n4], 0, 0, 0);
                __builtin_amdgcn_s_setprio(0);
                if (do_stage) {
                    asm volatile("s_waitcnt vmcnt(6)" ::: "memory");
                } else if (kt + 2 == KI) {
                    asm volatile("s_waitcnt vmcnt(0)" ::: "memory");
                }
                asm volatile("s_barrier" ::: "memory");
                c += 1; if (c >= 3) c = 0;
            }
        }

        if (MODE == 1) {
            const int tile_m = (mgrp * SUBS + s) * BM;
#pragma unroll
            for (int m4 = 0; m4 < 4; ++m4)
#pragma unroll
                for (int r = 0; r < 4; ++r) {
                    int m = tile_m + wm * 64 + m4 * 16 + quad * 4 + r;
#pragma unroll
                    for (int n4 = 0; n4 < 4; ++n4) {
                        int col = tile_n + wn * 64 + n4 * 16 + lr;
                        float v = acc[m4][n4][r];
                        v = v / (1.f + __expf(-v));
                        Hout[(uint64_t)m * N + col] = f2bf(v);
                    }
                }
            if (s + 1 < SUBS) {
#pragma unroll
                for (int i = 0; i < 4; i++)
#pragma unroll
                    for (int j = 0; j < 4; j++)
                        acc[i][j] = (f32x4){0.f, 0.f, 0.f, 0.f};
            }
        }
    }

    if (MODE == 2) {
        const int tile_m = mgrp * SUBS * BM;
#pragma unroll
        for (int m4 = 0; m4 < 4; ++m4)
#pragma unroll
            for (int r = 0; r < 4; ++r) {
                int m = tile_m + wm * 64 + m4 * 16 + quad * 4 + r;
                int grow = rowidx[m];
                float wgt = rw[m];
                uint64_t rb = (uint64_t)grow * D_;
#pragma unroll
                for (int n4 = 0; n4 < 4; ++n4) {
                    int col = tile_n + wn * 64 + n4 * 16 + lr;
                    Out[rb + col] = x[rb + col] + acc[m4][n4][r] * wgt;
                }
            }
    }
}

// ---------------------------------------------------------------------------
extern "C" void kernel_launch(void* const* d_in, const int* in_sizes, int n_in,
                              void* d_out, int out_size, void* d_ws, size_t ws_size,
                              hipStream_t stream) {
    const float* x  = (const float*)d_in[0];
    // d_in[1] = mask (unused: all-ones in setup, MLP ignores it)
    const float* Wr = (const float*)d_in[2];
    const float* W1 = (const float*)d_in[3];
    const float* W2 = (const float*)d_in[4];
    float* out = (float*)d_out;

    char* ws = (char*)d_ws;
    size_t off = 0;
    auto alloc = [&](size_t bytes) {
        char* p = ws + off;
        off = (off + bytes + 255) & ~(size_t)255;
        return p;
    };
    unsigned short* xb   = (unsigned short*)alloc((size_t)NTOK_ * D_ * 2);  // 33.5 MB
    unsigned short* W1bT = (unsigned short*)alloc((size_t)DFF_ * D_ * 2);   // 8.4 MB
    unsigned short* W2bT = (unsigned short*)alloc((size_t)D_ * DFF_ * 2);   // 8.4 MB
    unsigned short* H    = (unsigned short*)alloc((size_t)M_ * DFF_ * 2);   // 67 MB
    float* logits  = (float*)alloc(NTOK_ * 4);
    int*   rank    = (int*)alloc(NTOK_ * 4);
    int*   flags   = (int*)alloc(NTOK_ * 4);
    int*   rowidx  = (int*)alloc(M_ * 4);
    float* rwp     = (float*)alloc(M_ * 4);

    (void)hipMemsetAsync(rank, 0, NTOK_ * 4, stream);

    transpose2_bf16<<<2 * (DFF_ / 32) * (D_ / 32), dim3(32, 8), 0, stream>>>(
        W1, W1bT, W2, W2bT);
    router_kernel<<<NTOK_ / 4, 256, 0, stream>>>(x, Wr, logits, xb, out);
    rank_partial_kernel<<<512, 256, 0, stream>>>(logits, rank);
    compact_kernel<<<B_, 256, 0, stream>>>(logits, rank, flags, rowidx, rwp);
    loss_fused<<<1, 1024, 0, stream>>>(logits, flags, out + (size_t)NTOK_ * D_);
    // GEMM1: H[8192][4096] = silu(gather(xb) @ W1)  -- 256x256, persistent x2
    gemm1_256_kernel<DFF_, D_, 2><<<dim3(DFF_ / 256, M_ / 512), 512, 0, stream>>>(
        xb, W1bT, rowidx, H);
    // GEMM2: out[rowidx[m]] = x[rowidx[m]] + (H @ W2)[m] * rw[m]
    gemm_pipe_kernel<2, D_, DFF_, 1><<<dim3(D_ / 256, M_ / 128), 512, 0, stream>>>(
        H, W2bT, rowidx, rwp, x, nullptr, out);
}